// Round 1
// baseline (229.028 us; speedup 1.0000x reference)
//
#include <hip/hip_runtime.h>
#include <cmath>

#define BB 32
#define SS 256
#define HH 768

typedef __attribute__((ext_vector_type(8))) short bfrag8;
typedef __attribute__((ext_vector_type(4))) float accf4;

__device__ __forceinline__ unsigned short f2bf(float x) {   // RTNE fp32->bf16
    unsigned int b = __float_as_uint(x);
    return (unsigned short)((b + 0x7FFFu + ((b >> 16) & 1u)) >> 16);
}

__device__ __forceinline__ float bf2f(unsigned short u) {
    unsigned int b = ((unsigned int)u) << 16;
    return __uint_as_float(b);
}

__device__ __forceinline__ void gload16(const void* g, void* l) {
    __builtin_amdgcn_global_load_lds((const __attribute__((address_space(1))) void*)g,
                                     (__attribute__((address_space(3))) void*)l, 16, 0, 0);
}

// bf16 planes are 256 rows x 32 elems; each row = 4 fragments of 8.
// Swizzle: fragment (row, f) is stored at slot f ^ ((row>>1)&3)  (2-way = free).

// ---- normcvt: norms + normalized-bf16 packing (pure streaming, no atomics) ----
__global__ __launch_bounds__(256)
void normcvt_kernel(const float* __restrict__ Q, const float* __restrict__ K,
                    unsigned short* __restrict__ qws, unsigned short* __restrict__ kws) {
    const int wave = threadIdx.x >> 6, lane = threadIdx.x & 63;
    const bool isQ = blockIdx.x < 2048;          // rows 0..8191 = Q, else K
    const int rr = (blockIdx.x * 4 + wave) & 8191;
    const float4* src4 = isQ ? (const float4*)(Q + (size_t)rr * HH)
                             : (const float4*)(K + (size_t)rr * HH);
    float4 vv[3]; float s = 0.f;
#pragma unroll
    for (int c = 0; c < 3; ++c) {
        vv[c] = src4[lane + 64 * c];
        s += vv[c].x * vv[c].x + vv[c].y * vv[c].y + vv[c].z * vv[c].z + vv[c].w * vv[c].w;
    }
#pragma unroll
    for (int off = 1; off < 64; off <<= 1) s += __shfl_xor(s, off);
    float inv = 1.f / fmaxf(sqrtf(s), 1e-12f);

    const int b = rr >> 8, srow = rr & 255;
    unsigned short* dst = isQ ? qws : kws;
    // swizzled short-offset of this lane's 4 shorts within the 32-short row
    const int fp8 = (((((lane & 7) >> 1)) ^ ((srow >> 1) & 3)) << 3) + (lane & 1) * 4;
#pragma unroll
    for (int c = 0; c < 3; ++c) {
        int kc = (lane >> 3) + 8 * c;
        ushort4 o;
        o.x = f2bf(vv[c].x * inv); o.y = f2bf(vv[c].y * inv);
        o.z = f2bf(vv[c].z * inv); o.w = f2bf(vv[c].w * inv);
        *(ushort4*)(dst + (((size_t)b * 24 + kc) * 256 + srow) * 32 + fp8) = o;
    }
}

// ---- ksum: Ksum[j][h] = sum_t mask(t) * k_norm[j][t][h], read from bf16 planes ----
// grid = 32 j * 24 kc = 768 blocks; 256 threads: e = tid&31 (elem), tg = tid>>5 (t-group)
__global__ __launch_bounds__(256)
void ksum_kernel(const unsigned short* __restrict__ kws, const float* __restrict__ kmask,
                 unsigned short* __restrict__ ksumB) {
    __shared__ float red[8][32];
    const int j = blockIdx.x / 24, kc = blockIdx.x - j * 24;
    const int e = threadIdx.x & 31, tg = threadIdx.x >> 5;
    const unsigned short* base = kws + ((size_t)(j * 24 + kc)) * 8192;
    const float* km = kmask + j * SS;
    float s = 0.f;
    for (int t = tg; t < 256; t += 8) {
        if (km[t] > 0.f) {
            int pos = (((e >> 3) ^ ((t >> 1) & 3)) << 3) + (e & 7);
            s += bf2f(base[t * 32 + pos]);
        }
    }
    red[tg][e] = s;
    __syncthreads();
    if (tg == 0) {
        float tot = 0.f;
#pragma unroll
        for (int g = 0; g < 8; ++g) tot += red[g][e];
        ksumB[(size_t)(j * 24 + kc) * 32 + e] = f2bf(tot);
    }
}

// ---- main: banded QK^T + fused base (q.Ksum via broadcast-B MFMA) + epilogue ----
// Double-buffered LDS: stage kc+1 BEFORE computing kc; one barrier per iteration.
// The compiler's vmcnt(0) drain at the barrier then lands after ~600cy of compute.
__global__ __launch_bounds__(256, 2)
void mfma_kernel(const unsigned short* __restrict__ qws, const unsigned short* __restrict__ kws,
                 const float* __restrict__ qmask, const float* __restrict__ kmask,
                 const float* __restrict__ araw_p, const float* __restrict__ lscale_p,
                 const unsigned short* __restrict__ ksumB, float* __restrict__ out) {
    __shared__ short lq[2][8192];   // 2 x (256x32 bf16 plane, swizzled)
    __shared__ short lk[2][8192];
    __shared__ short lKsum[768];    // ksumB[j], [kc][32]
    __shared__ float sKm[256];
    __shared__ float wtab[13];
    __shared__ float sRed[4][2];
    __shared__ float sPart[4];
    __shared__ float sKcnt, sQden;

    const int tid = threadIdx.x;
    const int lane = tid & 63, w = tid >> 6;
    const int quad = lane >> 4, col = lane & 15;
    const int i = blockIdx.x >> 5, j = blockIdx.x & 31;

    const float alpha = log1pf(__expf(araw_p[0]));
    const float scale = __expf(lscale_p[0]);

    // ---- phase A ----
    float aq = qmask[i * SS + tid];
    float km = kmask[j * SS + tid];
    sKm[tid] = km;
    float c = (km > 0.f) ? 1.f : 0.f;
#pragma unroll
    for (int off = 1; off < 64; off <<= 1) { aq += __shfl_xor(aq, off); c += __shfl_xor(c, off); }
    if (lane == 0) { sRed[w][0] = aq; sRed[w][1] = c; }
    if (tid < 13) wtab[tid] = __expf(-alpha * (float)tid);
    if (tid < 192) ((ushort4*)lKsum)[tid] = ((const ushort4*)(ksumB + (size_t)j * HH))[tid];

    accf4 acc[4][3];
    accf4 accB[4];
#pragma unroll
    for (int a = 0; a < 4; ++a) {
        accB[a] = (accf4)0.f;
#pragma unroll
        for (int b = 0; b < 3; ++b) acc[a][b] = (accf4)0.f;
    }

    const size_t qb0 = (size_t)i * 24 * 8192;
    const size_t kb0 = (size_t)j * 24 * 8192;
    const int perm8 = ((quad ^ ((col >> 1) & 3)) << 3);   // swizzled fragment slot (shorts)

    const unsigned short* qsrc = qws + qb0 + w * 2048 + lane * 8;
    const unsigned short* ksrc = kws + kb0 + w * 2048 + lane * 8;

    // prologue: stage kc=0 into buffer 0
    {
        unsigned short* lqd = (unsigned short*)lq[0] + w * 2048;   // wave-uniform base
        unsigned short* lkd = (unsigned short*)lk[0] + w * 2048;
#pragma unroll
        for (int n = 0; n < 4; ++n) {
            gload16(qsrc + n * 512, lqd + n * 512);
            gload16(ksrc + n * 512, lkd + n * 512);
        }
    }
    __syncthreads();
    if (tid == 0) {
        sQden = fmaxf(sRed[0][0] + sRed[1][0] + sRed[2][0] + sRed[3][0], 1.f);
        sKcnt = sRed[0][1] + sRed[1][1] + sRed[2][1] + sRed[3][1];
    }

    // ---- K loop: 24 chunks of 32, software-pipelined ----
    int cur = 0;
    for (int kc = 0; kc < 24; ++kc) {
        if (kc < 23) {   // issue next-tile loads first; they fly during compute
            const unsigned short* qn = qsrc + (size_t)(kc + 1) * 8192;
            const unsigned short* kn = ksrc + (size_t)(kc + 1) * 8192;
            unsigned short* lqd = (unsigned short*)lq[cur ^ 1] + w * 2048;
            unsigned short* lkd = (unsigned short*)lk[cur ^ 1] + w * 2048;
#pragma unroll
            for (int n = 0; n < 4; ++n) {
                gload16(qn + n * 512, lqd + n * 512);
                gload16(kn + n * 512, lkd + n * 512);
            }
        }

        const short* cq = lq[cur];
        const short* ck = lk[cur];
        const bfrag8 kfrag = *(const bfrag8*)(lKsum + kc * 32 + quad * 8);  // broadcast
        bfrag8 bfr[6];
#pragma unroll
        for (int u = 0; u < 6; ++u) {
            int tb = 4 * w - 1 + u;
            if (tb >= 0 && tb <= 15)
                bfr[u] = *(const bfrag8*)(ck + (size_t)(tb * 16 + col) * 32 + perm8);
        }
#pragma unroll
        for (int sbl = 0; sbl < 4; ++sbl) {
            bfrag8 af = *(const bfrag8*)(cq + (size_t)((4 * w + sbl) * 16 + col) * 32 + perm8);
            accB[sbl] = __builtin_amdgcn_mfma_f32_16x16x32_bf16(af, kfrag, accB[sbl], 0, 0, 0);
#pragma unroll
            for (int dtb = 0; dtb < 3; ++dtb) {
                int tb = 4 * w + sbl - 1 + dtb;
                if (tb >= 0 && tb <= 15)
                    acc[sbl][dtb] = __builtin_amdgcn_mfma_f32_16x16x32_bf16(
                        af, bfr[sbl + dtb], acc[sbl][dtb], 0, 0, 0);
            }
        }
        __syncthreads();   // drains prefetch (issued pre-compute) + orders buffer reuse
        cur ^= 1;
    }

    // ---- epilogue: C/D layout col=lane&15 (t), row=quad*4+reg (s) ----
    const float kcnt = sKcnt;
    float part = 0.f;
#pragma unroll
    for (int sbl = 0; sbl < 4; ++sbl) {
        const int sbase = (4 * w + sbl) * 16 + quad * 4;
        float ns[4] = {0.f, 0.f, 0.f, 0.f}, ds[4] = {0.f, 0.f, 0.f, 0.f};
#pragma unroll
        for (int dtb = 0; dtb < 3; ++dtb) {
            int tb = 4 * w + sbl - 1 + dtb;
            if (tb < 0 || tb > 15) continue;
            int t = tb * 16 + col;
            float kmv = sKm[t];
#pragma unroll
            for (int reg = 0; reg < 4; ++reg) {
                int st = sbase + reg;
                int d = t - st;
                bool ok = (d >= -11) && (d <= 12) && (kmv > 0.f);
                int idx = d < 0 ? -d : d;
                idx = ok ? idx : 0;
                float raw = acc[sbl][dtb][reg];
                float e = ok ? expm1f(scale * raw * wtab[idx]) : 0.f;
                ns[reg] = fmaf(e, raw, ns[reg]);
                ds[reg] += e;
            }
        }
#pragma unroll
        for (int off = 1; off < 16; off <<= 1) {
#pragma unroll
            for (int reg = 0; reg < 4; ++reg) {
                ns[reg] += __shfl_xor(ns[reg], off);
                ds[reg] += __shfl_xor(ds[reg], off);
            }
        }
        if (col == 0) {
#pragma unroll
            for (int reg = 0; reg < 4; ++reg) {
                int st = sbase + reg;
                float qm = qmask[i * SS + st];
                float bse = accB[sbl][reg];      // fused base: all cols equal; col 0 lane has it
                float dtot = ds[reg] + kcnt;
                float v = (qm > 0.f && kcnt > 0.f) ? qm * (ns[reg] + bse) / dtot : 0.f;
                part += v;
            }
        }
    }
    part += __shfl_xor(part, 16);
    part += __shfl_xor(part, 32);
    if (lane == 0) sPart[w] = part;
    __syncthreads();
    if (tid == 0) out[i * BB + j] = (sPart[0] + sPart[1] + sPart[2] + sPart[3]) / sQden;
}

// ============ launcher ============

extern "C" void kernel_launch(void* const* d_in, const int* in_sizes, int n_in,
                              void* d_out, int out_size, void* d_ws, size_t ws_size,
                              hipStream_t stream) {
    const float* Q      = (const float*)d_in[0];
    const float* K      = (const float*)d_in[1];
    const float* qmask  = (const float*)d_in[2];
    const float* kmask  = (const float*)d_in[3];
    const float* araw   = (const float*)d_in[4];
    const float* lscale = (const float*)d_in[5];
    float* outp = (float*)d_out;

    unsigned short* ksumB = (unsigned short*)d_ws;            // 24576 us
    unsigned short* qws = ksumB + 24576;                      // 6291456 us
    unsigned short* kws = qws + 6291456;                      // 6291456 us

    normcvt_kernel<<<4096, 256, 0, stream>>>(Q, K, qws, kws);
    ksum_kernel<<<768, 256, 0, stream>>>(kws, kmask, ksumB);
    mfma_kernel<<<1024, 256, 0, stream>>>(qws, kws, qmask, kmask, araw, lscale, ksumB, outp);
}

// Round 2
// 175.804 us; speedup vs baseline: 1.3027x; 1.3027x over previous
//
#include <hip/hip_runtime.h>
#include <cmath>

#define BB 32
#define SS 256
#define HH 768

typedef __attribute__((ext_vector_type(8))) short bfrag8;
typedef __attribute__((ext_vector_type(4))) float accf4;

__device__ __forceinline__ unsigned short f2bf(float x) {   // RTNE fp32->bf16
    unsigned int b = __float_as_uint(x);
    return (unsigned short)((b + 0x7FFFu + ((b >> 16) & 1u)) >> 16);
}

__device__ __forceinline__ float bf2f(unsigned short u) {
    unsigned int b = ((unsigned int)u) << 16;
    return __uint_as_float(b);
}

// bf16 planes: [b][kc][srow][32], plain row-major (NO swizzle — all plane reads
// are per-lane register loads now, each wave instruction covers 1KB contiguous).

// ---- normcvt: norms + normalized-bf16 packing (pure streaming, no atomics) ----
__global__ __launch_bounds__(256)
void normcvt_kernel(const float* __restrict__ Q, const float* __restrict__ K,
                    unsigned short* __restrict__ qws, unsigned short* __restrict__ kws) {
    const int wave = threadIdx.x >> 6, lane = threadIdx.x & 63;
    const bool isQ = blockIdx.x < 2048;          // rows 0..8191 = Q, else K
    const int rr = (blockIdx.x * 4 + wave) & 8191;
    const float4* src4 = isQ ? (const float4*)(Q + (size_t)rr * HH)
                             : (const float4*)(K + (size_t)rr * HH);
    float4 vv[3]; float s = 0.f;
#pragma unroll
    for (int c = 0; c < 3; ++c) {
        vv[c] = src4[lane + 64 * c];
        s += vv[c].x * vv[c].x + vv[c].y * vv[c].y + vv[c].z * vv[c].z + vv[c].w * vv[c].w;
    }
#pragma unroll
    for (int off = 1; off < 64; off <<= 1) s += __shfl_xor(s, off);
    float inv = 1.f / fmaxf(sqrtf(s), 1e-12f);

    const int b = rr >> 8, srow = rr & 255;
    unsigned short* dst = isQ ? qws : kws;
    const int fp8 = (lane & 7) * 4;               // linear position within the 32-short row
#pragma unroll
    for (int c = 0; c < 3; ++c) {
        int kc = (lane >> 3) + 8 * c;
        ushort4 o;
        o.x = f2bf(vv[c].x * inv); o.y = f2bf(vv[c].y * inv);
        o.z = f2bf(vv[c].z * inv); o.w = f2bf(vv[c].w * inv);
        *(ushort4*)(dst + (((size_t)b * 24 + kc) * 256 + srow) * 32 + fp8) = o;
    }
}

// ---- ksum: Ksum[j][h] = sum_t mask(t) * k_norm[j][t][h], read from bf16 planes ----
// grid = 32 j * 24 kc = 768 blocks; 256 threads: e = tid&31 (elem), tg = tid>>5 (t-group)
__global__ __launch_bounds__(256)
void ksum_kernel(const unsigned short* __restrict__ kws, const float* __restrict__ kmask,
                 unsigned short* __restrict__ ksumB) {
    __shared__ float red[8][32];
    const int j = blockIdx.x / 24, kc = blockIdx.x - j * 24;
    const int e = threadIdx.x & 31, tg = threadIdx.x >> 5;
    const unsigned short* base = kws + ((size_t)(j * 24 + kc)) * 8192;
    const float* km = kmask + j * SS;
    float s = 0.f;
    for (int t = tg; t < 256; t += 8) {
        if (km[t] > 0.f) s += bf2f(base[t * 32 + e]);
    }
    red[tg][e] = s;
    __syncthreads();
    if (tg == 0) {
        float tot = 0.f;
#pragma unroll
        for (int g = 0; g < 8; ++g) tot += red[g][e];
        ksumB[(size_t)(j * 24 + kc) * 32 + e] = f2bf(tot);
    }
}

// ---- main: banded QK^T + fused base, NO LDS staging, NO barriers in the K loop ----
// Every fragment is a per-lane 16B global load (wave covers 1KB contiguous, L2-hot).
// Waves free-run; latency hidden by load-batch-then-MFMA + 3 blocks/CU TLP.
__global__ __launch_bounds__(256, 3)
void mfma_kernel(const unsigned short* __restrict__ qws, const unsigned short* __restrict__ kws,
                 const float* __restrict__ qmask, const float* __restrict__ kmask,
                 const float* __restrict__ araw_p, const float* __restrict__ lscale_p,
                 const unsigned short* __restrict__ ksumB, float* __restrict__ out) {
    __shared__ short lKsum[768]; // ksumB[j], [kc][32]
    __shared__ float sKm[256];
    __shared__ float wtab[13];
    __shared__ float sRed[4][2];
    __shared__ float sPart[4];
    __shared__ float sKcnt, sQden;

    const int tid = threadIdx.x;
    const int lane = tid & 63, w = tid >> 6;
    const int quad = lane >> 4, col = lane & 15;
    const int i = blockIdx.x >> 5, j = blockIdx.x & 31;

    const float alpha = log1pf(__expf(araw_p[0]));
    const float scale = __expf(lscale_p[0]);

    // ---- phase A ----
    float aq = qmask[i * SS + tid];
    float km = kmask[j * SS + tid];
    sKm[tid] = km;
    float c = (km > 0.f) ? 1.f : 0.f;
#pragma unroll
    for (int off = 1; off < 64; off <<= 1) { aq += __shfl_xor(aq, off); c += __shfl_xor(c, off); }
    if (lane == 0) { sRed[w][0] = aq; sRed[w][1] = c; }
    if (tid < 13) wtab[tid] = __expf(-alpha * (float)tid);
    if (tid < 192) ((ushort4*)lKsum)[tid] = ((const ushort4*)(ksumB + (size_t)j * HH))[tid];
    __syncthreads();
    if (tid == 0) {
        sQden = fmaxf(sRed[0][0] + sRed[1][0] + sRed[2][0] + sRed[3][0], 1.f);
        sKcnt = sRed[0][1] + sRed[1][1] + sRed[2][1] + sRed[3][1];
    }
    __syncthreads();   // lKsum + sKcnt visible; no barriers after this until the end

    accf4 acc[4][3];
    accf4 accB[4];
#pragma unroll
    for (int a = 0; a < 4; ++a) {
        accB[a] = (accf4)0.f;
#pragma unroll
        for (int b = 0; b < 3; ++b) acc[a][b] = (accf4)0.f;
    }

    // per-lane fragment base pointers (row = blk*16+col, elems quad*8..+8 of 32)
    const unsigned short* qp0 = qws + (size_t)i * 24 * 8192 + (size_t)(4 * w) * 512
                                    + col * 32 + quad * 8;
    const unsigned short* kp0 = kws + (size_t)j * 24 * 8192 + col * 32 + quad * 8;

    // ---- K loop: 24 chunks of 32, barrier-free ----
    for (int kc = 0; kc < 24; ++kc) {
        const unsigned short* qp = qp0 + (size_t)kc * 8192;
        const unsigned short* kp = kp0 + (size_t)kc * 8192;
        bfrag8 af[4];
#pragma unroll
        for (int sbl = 0; sbl < 4; ++sbl)
            af[sbl] = *(const bfrag8*)(qp + sbl * 512);
        bfrag8 bfr[6];
#pragma unroll
        for (int u = 0; u < 6; ++u) {
            int tb = 4 * w - 1 + u;            // wave-uniform guard, no divergence
            if (tb >= 0 && tb <= 15)
                bfr[u] = *(const bfrag8*)(kp + tb * 512);
        }
        const bfrag8 kfrag = *(const bfrag8*)(lKsum + kc * 32 + quad * 8);  // broadcast
#pragma unroll
        for (int sbl = 0; sbl < 4; ++sbl) {
            accB[sbl] = __builtin_amdgcn_mfma_f32_16x16x32_bf16(af[sbl], kfrag, accB[sbl], 0, 0, 0);
#pragma unroll
            for (int dtb = 0; dtb < 3; ++dtb) {
                int tb = 4 * w + sbl - 1 + dtb;
                if (tb >= 0 && tb <= 15)
                    acc[sbl][dtb] = __builtin_amdgcn_mfma_f32_16x16x32_bf16(
                        af[sbl], bfr[sbl + dtb], acc[sbl][dtb], 0, 0, 0);
            }
        }
    }

    // ---- epilogue: C/D layout col=lane&15 (t), row=quad*4+reg (s) ----
    const float kcnt = sKcnt;
    float part = 0.f;
#pragma unroll
    for (int sbl = 0; sbl < 4; ++sbl) {
        const int sbase = (4 * w + sbl) * 16 + quad * 4;
        float ns[4] = {0.f, 0.f, 0.f, 0.f}, ds[4] = {0.f, 0.f, 0.f, 0.f};
#pragma unroll
        for (int dtb = 0; dtb < 3; ++dtb) {
            int tb = 4 * w + sbl - 1 + dtb;
            if (tb < 0 || tb > 15) continue;
            int t = tb * 16 + col;
            float kmv = sKm[t];
#pragma unroll
            for (int reg = 0; reg < 4; ++reg) {
                int st = sbase + reg;
                int d = t - st;
                bool ok = (d >= -11) && (d <= 12) && (kmv > 0.f);
                int idx = d < 0 ? -d : d;
                idx = ok ? idx : 0;
                float raw = acc[sbl][dtb][reg];
                float e = ok ? expm1f(scale * raw * wtab[idx]) : 0.f;
                ns[reg] = fmaf(e, raw, ns[reg]);
                ds[reg] += e;
            }
        }
#pragma unroll
        for (int off = 1; off < 16; off <<= 1) {
#pragma unroll
            for (int reg = 0; reg < 4; ++reg) {
                ns[reg] += __shfl_xor(ns[reg], off);
                ds[reg] += __shfl_xor(ds[reg], off);
            }
        }
        if (col == 0) {
#pragma unroll
            for (int reg = 0; reg < 4; ++reg) {
                int st = sbase + reg;
                float qm = qmask[i * SS + st];
                float bse = accB[sbl][reg];      // fused base: all cols equal; col 0 lane has it
                float dtot = ds[reg] + kcnt;
                float v = (qm > 0.f && kcnt > 0.f) ? qm * (ns[reg] + bse) / dtot : 0.f;
                part += v;
            }
        }
    }
    part += __shfl_xor(part, 16);
    part += __shfl_xor(part, 32);
    if (lane == 0) sPart[w] = part;
    __syncthreads();
    if (tid == 0) out[i * BB + j] = (sPart[0] + sPart[1] + sPart[2] + sPart[3]) / sQden;
}

// ============ launcher ============

extern "C" void kernel_launch(void* const* d_in, const int* in_sizes, int n_in,
                              void* d_out, int out_size, void* d_ws, size_t ws_size,
                              hipStream_t stream) {
    const float* Q      = (const float*)d_in[0];
    const float* K      = (const float*)d_in[1];
    const float* qmask  = (const float*)d_in[2];
    const float* kmask  = (const float*)d_in[3];
    const float* araw   = (const float*)d_in[4];
    const float* lscale = (const float*)d_in[5];
    float* outp = (float*)d_out;

    unsigned short* ksumB = (unsigned short*)d_ws;            // 24576 us
    unsigned short* qws = ksumB + 24576;                      // 6291456 us
    unsigned short* kws = qws + 6291456;                      // 6291456 us

    normcvt_kernel<<<4096, 256, 0, stream>>>(Q, K, qws, kws);
    ksum_kernel<<<768, 256, 0, stream>>>(kws, kmask, ksumB);
    mfma_kernel<<<1024, 256, 0, stream>>>(qws, kws, qmask, kmask, araw, lscale, ksumB, outp);
}